// Round 3
// baseline (3131.122 us; speedup 1.0000x reference)
//
#include <hip/hip_runtime.h>
#include <hip/hip_bf16.h>

#define NB   4
#define NH   16
#define SEQ  1024
#define CH   2048
#define HDIM 128

// ---------------------------------------------------------------------------
// GEMM NT: out[m,n] = sum_k A[m,k] * B[n,k]   (A: [M,K], B: [N,K], row-major)
// 128x128 tile, BK=16, 256 threads, 8x8 microtile per thread.
// LDS stores tiles transposed As[k][m] (+4 pad: staging writes 2-way max).
// ---------------------------------------------------------------------------

__global__ __launch_bounds__(256)
void gemm_proj(const float* __restrict__ A, const float* __restrict__ B,
               float* __restrict__ out, int M, int N, int K) {
  __shared__ float As[16][132];
  __shared__ float Bs[16][132];
  const int tid = threadIdx.x;
  const int tx = tid & 15, ty = tid >> 4;
  const int m0 = blockIdx.y * 128, n0 = blockIdx.x * 128;

  float acc[8][8];
#pragma unroll
  for (int i = 0; i < 8; ++i)
#pragma unroll
    for (int j = 0; j < 8; ++j) acc[i][j] = 0.f;

  for (int k0 = 0; k0 < K; k0 += 16) {
#pragma unroll
    for (int p = 0; p < 2; ++p) {
      int f = tid + p * 256;          // float4 index into 128x16 tile
      int r = f >> 2, kq = f & 3;
      float4 a = *(const float4*)(A + (size_t)(m0 + r) * K + k0 + kq * 4);
      As[kq * 4 + 0][r] = a.x; As[kq * 4 + 1][r] = a.y;
      As[kq * 4 + 2][r] = a.z; As[kq * 4 + 3][r] = a.w;
      float4 b = *(const float4*)(B + (size_t)(n0 + r) * K + k0 + kq * 4);
      Bs[kq * 4 + 0][r] = b.x; Bs[kq * 4 + 1][r] = b.y;
      Bs[kq * 4 + 2][r] = b.z; Bs[kq * 4 + 3][r] = b.w;
    }
    __syncthreads();
#pragma unroll
    for (int kk = 0; kk < 16; ++kk) {
      float a[8], b[8];
      *(float4*)&a[0] = *(const float4*)&As[kk][ty * 8];
      *(float4*)&a[4] = *(const float4*)&As[kk][ty * 8 + 4];
      *(float4*)&b[0] = *(const float4*)&Bs[kk][tx * 8];
      *(float4*)&b[4] = *(const float4*)&Bs[kk][tx * 8 + 4];
#pragma unroll
      for (int i = 0; i < 8; ++i)
#pragma unroll
        for (int j = 0; j < 8; ++j)
          acc[i][j] = fmaf(a[i], b[j], acc[i][j]);
    }
    __syncthreads();
  }
#pragma unroll
  for (int i = 0; i < 8; ++i) {
    float* dst = out + (size_t)(m0 + ty * 8 + i) * N + n0 + tx * 8;
    *(float4*)dst = *(float4*)&acc[i][0];
    *(float4*)(dst + 4) = *(float4*)&acc[i][4];
  }
}

// Same GEMM, but epilogue scatters f = n0+n into Q/K/V [B,H,T,HD] layout.
// Tile width 128 == HD, so each col-tile maps to exactly one (which, h).
__global__ __launch_bounds__(256)
void gemm_qkv(const float* __restrict__ A, const float* __restrict__ B,
              float* __restrict__ Q, float* __restrict__ Kp, float* __restrict__ Vp) {
  const int K = CH;
  __shared__ float As[16][132];
  __shared__ float Bs[16][132];
  const int tid = threadIdx.x;
  const int tx = tid & 15, ty = tid >> 4;
  const int m0 = blockIdx.y * 128, n0 = blockIdx.x * 128;

  float acc[8][8];
#pragma unroll
  for (int i = 0; i < 8; ++i)
#pragma unroll
    for (int j = 0; j < 8; ++j) acc[i][j] = 0.f;

  for (int k0 = 0; k0 < K; k0 += 16) {
#pragma unroll
    for (int p = 0; p < 2; ++p) {
      int f = tid + p * 256;
      int r = f >> 2, kq = f & 3;
      float4 a = *(const float4*)(A + (size_t)(m0 + r) * K + k0 + kq * 4);
      As[kq * 4 + 0][r] = a.x; As[kq * 4 + 1][r] = a.y;
      As[kq * 4 + 2][r] = a.z; As[kq * 4 + 3][r] = a.w;
      float4 b = *(const float4*)(B + (size_t)(n0 + r) * K + k0 + kq * 4);
      Bs[kq * 4 + 0][r] = b.x; Bs[kq * 4 + 1][r] = b.y;
      Bs[kq * 4 + 2][r] = b.z; Bs[kq * 4 + 3][r] = b.w;
    }
    __syncthreads();
#pragma unroll
    for (int kk = 0; kk < 16; ++kk) {
      float a[8], b[8];
      *(float4*)&a[0] = *(const float4*)&As[kk][ty * 8];
      *(float4*)&a[4] = *(const float4*)&As[kk][ty * 8 + 4];
      *(float4*)&b[0] = *(const float4*)&Bs[kk][tx * 8];
      *(float4*)&b[4] = *(const float4*)&Bs[kk][tx * 8 + 4];
#pragma unroll
      for (int i = 0; i < 8; ++i)
#pragma unroll
        for (int j = 0; j < 8; ++j)
          acc[i][j] = fmaf(a[i], b[j], acc[i][j]);
    }
    __syncthreads();
  }

  const int which = n0 >> 11;          // n0 / 2048: 0=Q 1=K 2=V
  const int h = (n0 >> 7) & 15;        // head within the 2048 block
  float* dst0 = (which == 0) ? Q : (which == 1) ? Kp : Vp;
#pragma unroll
  for (int i = 0; i < 8; ++i) {
    int m = m0 + ty * 8 + i;
    int bb = m >> 10, t = m & 1023;
    float* dst = dst0 + (((size_t)(bb * NH + h)) * SEQ + t) * HDIM + tx * 8;
    *(float4*)dst = *(float4*)&acc[i][0];
    *(float4*)(dst + 4) = *(float4*)&acc[i][4];
  }
}

// ---------------------------------------------------------------------------
// Flash-style attention, fp32. Block = 256 threads = 32 q-rows x 8 lanes/row.
// Each lane owns d-slice {32*i + 4*sub + r}: strided float4s -> conflict-free
// ds_read_b128 (8 distinct 16B addrs cover all 32 banks; same-sub broadcasts).
// K/V tiles 64x128 staged in exactly 64 KB LDS. Mask bias via __shfl.
// Y written as [B,T,C] (c = h*128+d) so the proj GEMM reads it contiguously.
// ---------------------------------------------------------------------------
__global__ __launch_bounds__(256)
void attn_fwd(const float* __restrict__ Q, const float* __restrict__ Kp,
              const float* __restrict__ Vp, const int* __restrict__ mask,
              float* __restrict__ Y) {
  __shared__ float Ks[64][128];
  __shared__ float Vs[64][128];
  const int tid = threadIdx.x;
  const int sub = tid & 7;
  const int row = tid >> 3;                 // 0..31
  const int bh = blockIdx.y;                // b*NH + h
  const int b = bh >> 4, h = bh & 15;
  const int qr = blockIdx.x * 32 + row;

  const float scale = 0.08838834764831843f; // 1/sqrt(128)

  const float* qptr = Q + ((size_t)bh * SEQ + qr) * HDIM;
  float4 qf[4];
#pragma unroll
  for (int i = 0; i < 4; ++i) {
    qf[i] = *(const float4*)(qptr + 32 * i + 4 * sub);
    qf[i].x *= scale; qf[i].y *= scale; qf[i].z *= scale; qf[i].w *= scale;
  }

  float4 acc[4];
#pragma unroll
  for (int i = 0; i < 4; ++i) acc[i] = make_float4(0.f, 0.f, 0.f, 0.f);
  float mval = -3.0e38f, lsum = 0.f;

  const float* kbase = Kp + (size_t)bh * SEQ * HDIM;
  const float* vbase = Vp + (size_t)bh * SEQ * HDIM;
  const int* mrow = mask + b * SEQ + (tid & 63);

  for (int kt = 0; kt < SEQ; kt += 64) {
    __syncthreads();   // previous tile fully consumed before overwrite
#pragma unroll
    for (int p = 0; p < 8; ++p) {
      int f = tid + p * 256;   // float4 index into 64x128 tile
      ((float4*)Ks)[f] = *(const float4*)(kbase + (size_t)kt * HDIM + f * 4);
      ((float4*)Vs)[f] = *(const float4*)(vbase + (size_t)kt * HDIM + f * 4);
    }
    // lane l of every wave holds bias for k-position kt+l
    float bv = mrow[kt] ? 0.f : -1.0e30f;
    __syncthreads();

    for (int j = 0; j < 64; ++j) {
      const float4* k4 = (const float4*)&Ks[j][0];
      float s = 0.f;
#pragma unroll
      for (int i = 0; i < 4; ++i) {
        float4 kv = k4[8 * i + sub];
        s = fmaf(qf[i].x, kv.x, s); s = fmaf(qf[i].y, kv.y, s);
        s = fmaf(qf[i].z, kv.z, s); s = fmaf(qf[i].w, kv.w, s);
      }
      s += __shfl_xor(s, 1); s += __shfl_xor(s, 2); s += __shfl_xor(s, 4);
      s += __shfl(bv, j);

      float mnew = fmaxf(mval, s);
      float p = __expf(s - mnew);
      float corr = __expf(mval - mnew);
      lsum = lsum * corr + p;
      mval = mnew;

      const float4* v4 = (const float4*)&Vs[j][0];
#pragma unroll
      for (int i = 0; i < 4; ++i) {
        float4 vv = v4[8 * i + sub];
        acc[i].x = acc[i].x * corr + p * vv.x;
        acc[i].y = acc[i].y * corr + p * vv.y;
        acc[i].z = acc[i].z * corr + p * vv.z;
        acc[i].w = acc[i].w * corr + p * vv.w;
      }
    }
  }

  float inv = 1.0f / lsum;
  float* yptr = Y + ((size_t)(b * SEQ + qr)) * CH + h * HDIM;
#pragma unroll
  for (int i = 0; i < 4; ++i) {
    float4 o = acc[i];
    o.x *= inv; o.y *= inv; o.z *= inv; o.w *= inv;
    *(float4*)(yptr + 32 * i + 4 * sub) = o;
  }
}

// ---------------------------------------------------------------------------
extern "C" void kernel_launch(void* const* d_in, const int* in_sizes, int n_in,
                              void* d_out, int out_size, void* d_ws, size_t ws_size,
                              hipStream_t stream) {
  const float* x      = (const float*)d_in[0];   // [B,T,C]
  const float* w_attn = (const float*)d_in[1];   // [3C,C]
  const float* w_proj = (const float*)d_in[2];   // [C,C]
  const int*   mask   = (const int*)d_in[3];     // [B,T]
  float* out = (float*)d_out;                    // [B,T,C]
  float* ws  = (float*)d_ws;

  const size_t qkv_elems = (size_t)NB * NH * SEQ * HDIM;  // 8M floats each
  float* Qw = ws;
  float* Kw = ws + qkv_elems;
  float* Vw = ws + 2 * qkv_elems;
  float* Yw = ws + 3 * qkv_elems;                // [B,T,C], 8M floats

  dim3 blk(256);
  // QKV projection: M=4096, N=6144, K=2048
  gemm_qkv<<<dim3(6144 / 128, 4096 / 128), blk, 0, stream>>>(x, w_attn, Qw, Kw, Vw);
  // Attention: one block per (32 q-rows, b*h)
  attn_fwd<<<dim3(SEQ / 32, NB * NH), blk, 0, stream>>>(Qw, Kw, Vw, mask, Yw);
  // Output projection: M=4096, N=2048, K=2048
  gemm_proj<<<dim3(2048 / 128, 4096 / 128), blk, 0, stream>>>(Yw, w_proj, out, NB * SEQ, CH, CH);
}

// Round 7
// 853.155 us; speedup vs baseline: 3.6701x; 3.6701x over previous
//
#include <hip/hip_runtime.h>
#include <hip/hip_bf16.h>

#define NB   4
#define NH   16
#define SEQ  1024
#define CH   2048
#define HDIM 128

typedef float f32x4 __attribute__((ext_vector_type(4)));
typedef short short8 __attribute__((ext_vector_type(8)));

// fp32 -> bf16 round-to-nearest-even
static __device__ __forceinline__ unsigned short f2bf(float f) {
  unsigned u = __builtin_bit_cast(unsigned, f);
  u += 0x7FFFu + ((u >> 16) & 1u);
  return (unsigned short)(u >> 16);
}

__global__ __launch_bounds__(256)
void cast_bf16(const float* __restrict__ in, unsigned short* __restrict__ out, int n4) {
  int i = blockIdx.x * 256 + threadIdx.x;
  int stride = gridDim.x * 256;
  for (; i < n4; i += stride) {
    float4 v = ((const float4*)in)[i];
    ushort4 o;
    o.x = f2bf(v.x); o.y = f2bf(v.y); o.z = f2bf(v.z); o.w = f2bf(v.w);
    ((ushort4*)out)[i] = o;
  }
}

// ---------------------------------------------------------------------------
// bf16 NT GEMM core: out[m,n] = sum_k A[m,k]*B[n,k].  128x128 tile, BK=64,
// 4 waves (2x2), each wave 64x64 = 4x4 frags of mfma_f32_16x16x32_bf16.
// A/B staged [row][k] in LDS (pad 64->72 shorts: 16B-aligned rows, <=2-way
// banks on frag ds_read_b128). A- and B-frags use the SAME per-lane k-chunk
// (lg*8..+7): any HW k-permutation cancels between operands.
// ---------------------------------------------------------------------------
__device__ __forceinline__ void gemm_tile_core(
    const unsigned short* __restrict__ A, const unsigned short* __restrict__ B,
    int K, int m0, int n0, short* As, short* Bs, f32x4 acc[4][4]) {
  const int tid = threadIdx.x;
  const int lane = tid & 63, wid = tid >> 6;
  const int wr = wid >> 1, wc = wid & 1;
  const int lr = lane & 15, lg = lane >> 4;

  const unsigned short* ga = A + (size_t)(m0 + (tid >> 1)) * K + (tid & 1) * 32;
  const unsigned short* gb = B + (size_t)(n0 + (tid >> 1)) * K + (tid & 1) * 32;
  short* wA = As + (tid >> 1) * 72 + (tid & 1) * 32;
  short* wB = Bs + (tid >> 1) * 72 + (tid & 1) * 32;

  for (int k0 = 0; k0 < K; k0 += 64) {
    uint4 va[4], vb[4];
#pragma unroll
    for (int j = 0; j < 4; ++j) {
      va[j] = *(const uint4*)(ga + k0 + j * 8);
      vb[j] = *(const uint4*)(gb + k0 + j * 8);
    }
    __syncthreads();               // prior frag reads done before overwrite
#pragma unroll
    for (int j = 0; j < 4; ++j) {
      *(uint4*)(wA + j * 8) = va[j];
      *(uint4*)(wB + j * 8) = vb[j];
    }
    __syncthreads();
#pragma unroll
    for (int kc = 0; kc < 2; ++kc) {
      short8 af[4], bf[4];
#pragma unroll
      for (int f = 0; f < 4; ++f) {
        af[f] = *(const short8*)(As + (wr * 64 + f * 16 + lr) * 72 + kc * 32 + lg * 8);
        bf[f] = *(const short8*)(Bs + (wc * 64 + f * 16 + lr) * 72 + kc * 32 + lg * 8);
      }
#pragma unroll
      for (int fm = 0; fm < 4; ++fm)
#pragma unroll
        for (int fn = 0; fn < 4; ++fn)
          acc[fm][fn] = __builtin_amdgcn_mfma_f32_16x16x32_bf16(af[fm], bf[fn], acc[fm][fn], 0, 0, 0);
    }
  }
  __syncthreads();                 // epilogue may reuse LDS
}

// QKV projection: A=xb [4096][2048], B=wab [6144][2048].
// Epilogue: Q (scaled by 1/sqrt(128)) and K -> bf16 [b,h,t,d]; V -> bf16
// TRANSPOSED [b,h,d,t] via an LDS transpose for coalesced stores.
__global__ __launch_bounds__(256)
void gemm_qkv_bf16(const unsigned short* __restrict__ xb, const unsigned short* __restrict__ wab,
                   unsigned short* __restrict__ Qb, unsigned short* __restrict__ Kb,
                   unsigned short* __restrict__ Vtb) {
  __shared__ short smem[2 * 128 * 72];
  short* As = smem;
  short* Bs = smem + 128 * 72;
  f32x4 acc[4][4];
#pragma unroll
  for (int i = 0; i < 4; ++i)
#pragma unroll
    for (int j = 0; j < 4; ++j) acc[i][j] = (f32x4){0.f, 0.f, 0.f, 0.f};

  const int m0 = blockIdx.y * 128, n0 = blockIdx.x * 128;
  gemm_tile_core(xb, wab, CH, m0, n0, As, Bs, acc);

  const int tid = threadIdx.x, lane = tid & 63, wid = tid >> 6;
  const int wr = wid >> 1, wc = wid & 1, lr = lane & 15, lg = lane >> 4;
  const int which = n0 >> 11;          // 0=Q 1=K 2=V
  const int h = (n0 >> 7) & 15;
  const int bb = m0 >> 10, t0 = m0 & 1023;

  if (which < 2) {
    unsigned short* dst0 = (which == 0) ? Qb : Kb;
    const float sc = (which == 0) ? 0.08838834764831843f : 1.0f;
#pragma unroll
    for (int fm = 0; fm < 4; ++fm)
#pragma unroll
      for (int fn = 0; fn < 4; ++fn)
#pragma unroll
        for (int r = 0; r < 4; ++r) {
          int tloc = wr * 64 + fm * 16 + lg * 4 + r;
          int d = wc * 64 + fn * 16 + lr;
          dst0[(((size_t)(bb * NH + h)) * SEQ + t0 + tloc) * HDIM + d] =
              f2bf(acc[fm][fn][r] * sc);
        }
  } else {
    short* vt = smem;                  // [128 d][136] transpose buffer
#pragma unroll
    for (int fm = 0; fm < 4; ++fm)
#pragma unroll
      for (int fn = 0; fn < 4; ++fn)
#pragma unroll
        for (int r = 0; r < 4; ++r)
          vt[(wc * 64 + fn * 16 + lr) * 136 + wr * 64 + fm * 16 + lg * 4 + r] =
              (short)f2bf(acc[fm][fn][r]);
    __syncthreads();
    int dd = tid >> 1, sg = tid & 1;
    unsigned short* gdst = Vtb + (((size_t)(bb * NH + h)) * HDIM + dd) * SEQ + t0 + sg * 64;
    const short* src = vt + dd * 136 + sg * 64;
#pragma unroll
    for (int j = 0; j < 8; ++j)        // FIX: was j<4 — left half of each 64-span unwritten
      *(uint4*)(gdst + j * 8) = *(const uint4*)(src + j * 8);
  }
}

// Output projection: A=Yb [4096][2048], B=wpb [2048][2048], out fp32.
__global__ __launch_bounds__(256)
void gemm_proj_bf16(const unsigned short* __restrict__ Yb, const unsigned short* __restrict__ wpb,
                    float* __restrict__ out) {
  __shared__ short smem[2 * 128 * 72];
  short* As = smem;
  short* Bs = smem + 128 * 72;
  f32x4 acc[4][4];
#pragma unroll
  for (int i = 0; i < 4; ++i)
#pragma unroll
    for (int j = 0; j < 4; ++j) acc[i][j] = (f32x4){0.f, 0.f, 0.f, 0.f};

  const int m0 = blockIdx.y * 128, n0 = blockIdx.x * 128;
  gemm_tile_core(Yb, wpb, CH, m0, n0, As, Bs, acc);

  const int tid = threadIdx.x, lane = tid & 63, wid = tid >> 6;
  const int wr = wid >> 1, wc = wid & 1, lr = lane & 15, lg = lane >> 4;
#pragma unroll
  for (int fm = 0; fm < 4; ++fm)
#pragma unroll
    for (int fn = 0; fn < 4; ++fn)
#pragma unroll
      for (int r = 0; r < 4; ++r)
        out[(size_t)(m0 + wr * 64 + fm * 16 + lg * 4 + r) * CH + n0 + wc * 64 + fn * 16 + lr] =
            acc[fm][fn][r];
}

// ---------------------------------------------------------------------------
// MFMA flash attention. Block = 256 = 4 waves; wave owns 16 q-rows; KV tile 32.
// QK^T: A=Q(regs), B=K(LDS [kpos][d] pad 136). Online softmax wave-parallel
// (shfl_xor over the 16 col-lanes). P -> LDS (per-wave) -> PV: A=P, B=V from
// Vt LDS [d][kpos] pad 40. All frag reads are aligned ds_read_b128, <=2-way.
// ---------------------------------------------------------------------------
__global__ __launch_bounds__(256)
void attn_mfma(const unsigned short* __restrict__ Qb, const unsigned short* __restrict__ Kb,
               const unsigned short* __restrict__ Vtb, const int* __restrict__ mask,
               unsigned short* __restrict__ Yb) {
  __shared__ short Kls[32 * 136];
  __shared__ short Vls[128 * 40];
  __shared__ short Pls[4 * 16 * 40];
  const int tid = threadIdx.x, lane = tid & 63, wid = tid >> 6;
  const int lr = lane & 15, lg = lane >> 4;
  const int bh = blockIdx.y, b = bh >> 4, h = bh & 15;
  const int q0 = blockIdx.x * 64 + wid * 16;   // wave's first q-row (t index)

  short8 qf[4];
  const unsigned short* qptr = Qb + ((size_t)bh * SEQ + q0 + lr) * HDIM + lg * 8;
#pragma unroll
  for (int dc = 0; dc < 4; ++dc) qf[dc] = *(const short8*)(qptr + dc * 32);

  f32x4 O[8];
#pragma unroll
  for (int i = 0; i < 8; ++i) O[i] = (f32x4){0.f, 0.f, 0.f, 0.f};
  float mrow[4] = {-3.0e38f, -3.0e38f, -3.0e38f, -3.0e38f};
  float lrow[4] = {0.f, 0.f, 0.f, 0.f};

  const unsigned short* kbase = Kb + (size_t)bh * SEQ * HDIM;
  const unsigned short* vbase = Vtb + (size_t)bh * HDIM * SEQ;
  short* Pw = Pls + wid * (16 * 40);
  const int* maskrow = mask + b * SEQ;

  for (int kt = 0; kt < SEQ; kt += 32) {
    __syncthreads();
    {   // stage K tile [32][128] and Vt tile [128][32]
      int r = tid >> 3, s = tid & 7;
      const unsigned short* g = kbase + (size_t)(kt + r) * HDIM + s * 16;
      uint4 u0 = *(const uint4*)g, u1 = *(const uint4*)(g + 8);
      *(uint4*)(Kls + r * 136 + s * 16) = u0;
      *(uint4*)(Kls + r * 136 + s * 16 + 8) = u1;
      int d = tid >> 1, s2 = tid & 1;
      const unsigned short* gv = vbase + (size_t)d * SEQ + kt + s2 * 16;
      uint4 v0 = *(const uint4*)gv, v1 = *(const uint4*)(gv + 8);
      *(uint4*)(Vls + d * 40 + s2 * 16) = v0;
      *(uint4*)(Vls + d * 40 + s2 * 16 + 8) = v1;
    }
    __syncthreads();

    // QK^T: S[16 q][32 kpos] in two col-frags
    f32x4 s0 = (f32x4){0.f, 0.f, 0.f, 0.f}, s1 = (f32x4){0.f, 0.f, 0.f, 0.f};
#pragma unroll
    for (int dc = 0; dc < 4; ++dc) {
      short8 k0f = *(const short8*)(Kls + lr * 136 + dc * 32 + lg * 8);
      short8 k1f = *(const short8*)(Kls + (16 + lr) * 136 + dc * 32 + lg * 8);
      s0 = __builtin_amdgcn_mfma_f32_16x16x32_bf16(qf[dc], k0f, s0, 0, 0, 0);
      s1 = __builtin_amdgcn_mfma_f32_16x16x32_bf16(qf[dc], k1f, s1, 0, 0, 0);
    }

    float b0 = maskrow[kt + lr] ? 0.f : -1.0e30f;
    float b1 = maskrow[kt + 16 + lr] ? 0.f : -1.0e30f;
    float corr[4];
#pragma unroll
    for (int r = 0; r < 4; ++r) {
      float a0 = s0[r] + b0, a1 = s1[r] + b1;
      float tm = fmaxf(a0, a1);
      tm = fmaxf(tm, __shfl_xor(tm, 1));
      tm = fmaxf(tm, __shfl_xor(tm, 2));
      tm = fmaxf(tm, __shfl_xor(tm, 4));
      tm = fmaxf(tm, __shfl_xor(tm, 8));
      float mn = fmaxf(mrow[r], tm);
      corr[r] = __expf(mrow[r] - mn);
      float p0 = __expf(a0 - mn), p1 = __expf(a1 - mn);
      mrow[r] = mn;
      float rs = p0 + p1;
      rs += __shfl_xor(rs, 1);
      rs += __shfl_xor(rs, 2);
      rs += __shfl_xor(rs, 4);
      rs += __shfl_xor(rs, 8);
      lrow[r] = lrow[r] * corr[r] + rs;
      Pw[(lg * 4 + r) * 40 + lr] = (short)f2bf(p0);
      Pw[(lg * 4 + r) * 40 + 16 + lr] = (short)f2bf(p1);
    }
#pragma unroll
    for (int db = 0; db < 8; ++db)
#pragma unroll
      for (int r = 0; r < 4; ++r) O[db][r] *= corr[r];

    short8 pa = *(const short8*)(Pw + lr * 40 + lg * 8);
#pragma unroll
    for (int db = 0; db < 8; ++db) {
      short8 vb = *(const short8*)(Vls + (db * 16 + lr) * 40 + lg * 8);
      O[db] = __builtin_amdgcn_mfma_f32_16x16x32_bf16(pa, vb, O[db], 0, 0, 0);
    }
  }

  float inv[4];
#pragma unroll
  for (int r = 0; r < 4; ++r) inv[r] = 1.0f / lrow[r];
  unsigned short* ybase = Yb + ((size_t)(b * SEQ + q0)) * CH + h * HDIM;
#pragma unroll
  for (int db = 0; db < 8; ++db)
#pragma unroll
    for (int r = 0; r < 4; ++r)
      ybase[(size_t)(lg * 4 + r) * CH + db * 16 + lr] = f2bf(O[db][r] * inv[r]);
}

// ---------------------------------------------------------------------------
extern "C" void kernel_launch(void* const* d_in, const int* in_sizes, int n_in,
                              void* d_out, int out_size, void* d_ws, size_t ws_size,
                              hipStream_t stream) {
  const float* x      = (const float*)d_in[0];   // [B,T,C]
  const float* w_attn = (const float*)d_in[1];   // [3C,C]
  const float* w_proj = (const float*)d_in[2];   // [C,C]
  const int*   mask   = (const int*)d_in[3];     // [B,T]
  float* out = (float*)d_out;                    // [B,T,C] fp32

  char* ws = (char*)d_ws;
  unsigned short* xb  = (unsigned short*)(ws);                    // 16.78 MB
  unsigned short* wab = (unsigned short*)(ws + 16777216);         // 25.17 MB
  unsigned short* wpb = (unsigned short*)(ws + 41943040);         // 8.39 MB
  unsigned short* Qb  = (unsigned short*)(ws + 50331648);         // 16.78 MB
  unsigned short* Kb  = (unsigned short*)(ws + 67108864);         // 16.78 MB
  unsigned short* Vtb = (unsigned short*)(ws + 83886080);         // 16.78 MB
  unsigned short* Yb  = (unsigned short*)(ws + 100663296);        // 16.78 MB -> 117.44 MB total

  cast_bf16<<<2048, 256, 0, stream>>>(x, xb, (NB * SEQ * CH) / 4);
  cast_bf16<<<2048, 256, 0, stream>>>(w_attn, wab, (3 * CH * CH) / 4);
  cast_bf16<<<2048, 256, 0, stream>>>(w_proj, wpb, (CH * CH) / 4);

  gemm_qkv_bf16<<<dim3(3 * CH / 128, NB * SEQ / 128), 256, 0, stream>>>(xb, wab, Qb, Kb, Vtb);
  attn_mfma<<<dim3(SEQ / 64, NB * NH), 256, 0, stream>>>(Qb, Kb, Vtb, mask, Yb);
  gemm_proj_bf16<<<dim3(CH / 128, NB * SEQ / 128), 256, 0, stream>>>(Yb, wpb, out);
}

// Round 8
// 470.590 us; speedup vs baseline: 6.6536x; 1.8129x over previous
//
#include <hip/hip_runtime.h>
#include <hip/hip_bf16.h>

#define NB   4
#define NH   16
#define SEQ  1024
#define CH   2048
#define HDIM 128

typedef float f32x4 __attribute__((ext_vector_type(4)));
typedef short short8 __attribute__((ext_vector_type(8)));

// fp32 -> bf16 round-to-nearest-even
static __device__ __forceinline__ unsigned short f2bf(float f) {
  unsigned u = __builtin_bit_cast(unsigned, f);
  u += 0x7FFFu + ((u >> 16) & 1u);
  return (unsigned short)(u >> 16);
}

// async global->LDS, 16B per lane: LDS dest = wave-uniform base + lane*16,
// global src = per-lane address.
#define GLOAD16(g, l)                                                        \
  __builtin_amdgcn_global_load_lds(                                          \
      (const __attribute__((address_space(1))) void*)(g),                    \
      (__attribute__((address_space(3))) void*)(l), 16, 0, 0)

__global__ __launch_bounds__(256)
void cast_bf16(const float* __restrict__ in, unsigned short* __restrict__ out, int n4) {
  int i = blockIdx.x * 256 + threadIdx.x;
  int stride = gridDim.x * 256;
  for (; i < n4; i += stride) {
    float4 v = ((const float4*)in)[i];
    ushort4 o;
    o.x = f2bf(v.x); o.y = f2bf(v.y); o.z = f2bf(v.z); o.w = f2bf(v.w);
    ((ushort4*)out)[i] = o;
  }
}

// ---------------------------------------------------------------------------
// bf16 NT GEMM core (m97-class): out[m,n] = sum_k A[m,k]*B[n,k].
// 128x128 tile, BK=64, 4 waves (2x2), 4x4 frags of mfma_f32_16x16x32_bf16.
// Staging: global_load_lds width-16, LINEAR LDS [128 rows][64 k-shorts].
// Chunk c (0..15) = rows c*8..c*8+7 -> LDS bytes c*1024 + lane*16;
// lane l: row c*8+(l>>3), k-shorts (l&7)*8. 2-barrier loop; compiler drains
// vmcnt(0) at the barrier. Frag reads are 16B-aligned ds_read_b128
// (16-way banks on linear layout — accepted per m97's 874 TF).
// ---------------------------------------------------------------------------
__device__ __forceinline__ void gemm_core_glds(
    const unsigned short* __restrict__ A, const unsigned short* __restrict__ B,
    int K, int m0, int n0, short* As, short* Bs, f32x4 acc[4][4]) {
  const int tid = threadIdx.x, lane = tid & 63, wid = tid >> 6;
  const int wr = wid >> 1, wc = wid & 1, lr = lane & 15, lg = lane >> 4;
  const int sr = lane >> 3;          // row within 8-row chunk
  const int sk = (lane & 7) * 8;     // k-short offset

  for (int k0 = 0; k0 < K; k0 += 64) {
    __syncthreads();                 // prev compute done, LDS free
#pragma unroll
    for (int p = 0; p < 4; ++p) {
      int c = wid * 4 + p;           // wave-uniform chunk id
      GLOAD16(A + (size_t)(m0 + c * 8 + sr) * K + k0 + sk, As + c * 512);
      GLOAD16(B + (size_t)(n0 + c * 8 + sr) * K + k0 + sk, Bs + c * 512);
    }
    __syncthreads();                 // vmcnt(0) drain -> tile visible
#pragma unroll
    for (int kc = 0; kc < 2; ++kc) {
      short8 af[4], bf[4];
#pragma unroll
      for (int f = 0; f < 4; ++f) {
        af[f] = *(const short8*)(As + (wr * 64 + f * 16 + lr) * 64 + kc * 32 + lg * 8);
        bf[f] = *(const short8*)(Bs + (wc * 64 + f * 16 + lr) * 64 + kc * 32 + lg * 8);
      }
#pragma unroll
      for (int fm = 0; fm < 4; ++fm)
#pragma unroll
        for (int fn = 0; fn < 4; ++fn)
          acc[fm][fn] = __builtin_amdgcn_mfma_f32_16x16x32_bf16(af[fm], bf[fn], acc[fm][fn], 0, 0, 0);
    }
  }
  __syncthreads();                   // epilogue reuses LDS
}

// QKV projection: A=xb [4096][2048], B=wab [6144][2048].
// ALL epilogues route through LDS -> full-line uint4 stores (no 2B scatter).
__global__ __launch_bounds__(256)
void gemm_qkv_bf16(const unsigned short* __restrict__ xb, const unsigned short* __restrict__ wab,
                   unsigned short* __restrict__ Qb, unsigned short* __restrict__ Kb,
                   unsigned short* __restrict__ Vtb) {
  __shared__ short smem[17408];      // 34816 B: staging 16384 sh | epilogue 128x136
  short* As = smem;
  short* Bs = smem + 8192;
  f32x4 acc[4][4];
#pragma unroll
  for (int i = 0; i < 4; ++i)
#pragma unroll
    for (int j = 0; j < 4; ++j) acc[i][j] = (f32x4){0.f, 0.f, 0.f, 0.f};

  const int m0 = blockIdx.y * 128, n0 = blockIdx.x * 128;
  gemm_core_glds(xb, wab, CH, m0, n0, As, Bs, acc);

  const int tid = threadIdx.x, lane = tid & 63, wid = tid >> 6;
  const int wr = wid >> 1, wc = wid & 1, lr = lane & 15, lg = lane >> 4;
  const int which = n0 >> 11;        // 0=Q 1=K 2=V
  const int h = (n0 >> 7) & 15;
  const int bb = m0 >> 10, t0 = m0 & 1023;

  if (which < 2) {
    unsigned short* dst0 = (which == 0) ? Qb : Kb;
    const float sc = (which == 0) ? 0.08838834764831843f : 1.0f;
    // acc -> LDS [t 128][d 136]
#pragma unroll
    for (int fm = 0; fm < 4; ++fm)
#pragma unroll
      for (int fn = 0; fn < 4; ++fn)
#pragma unroll
        for (int r = 0; r < 4; ++r)
          smem[(wr * 64 + fm * 16 + lg * 4 + r) * 136 + wc * 64 + fn * 16 + lr] =
              (short)f2bf(acc[fm][fn][r] * sc);
    __syncthreads();
    int row = tid >> 1, sg = tid & 1;          // 128B per thread, coalesced
    unsigned short* dst = dst0 + (((size_t)(bb * NH + h)) * SEQ + t0 + row) * HDIM + sg * 64;
    const short* src = smem + row * 136 + sg * 64;
#pragma unroll
    for (int j = 0; j < 8; ++j)
      *(uint4*)(dst + j * 8) = *(const uint4*)(src + j * 8);
  } else {
    // V transposed: LDS [d 128][t 136]
#pragma unroll
    for (int fm = 0; fm < 4; ++fm)
#pragma unroll
      for (int fn = 0; fn < 4; ++fn)
#pragma unroll
        for (int r = 0; r < 4; ++r)
          smem[(wc * 64 + fn * 16 + lr) * 136 + wr * 64 + fm * 16 + lg * 4 + r] =
              (short)f2bf(acc[fm][fn][r]);
    __syncthreads();
    int dd = tid >> 1, sg = tid & 1;
    unsigned short* gdst = Vtb + (((size_t)(bb * NH + h)) * HDIM + dd) * SEQ + t0 + sg * 64;
    const short* src = smem + dd * 136 + sg * 64;
#pragma unroll
    for (int j = 0; j < 8; ++j)
      *(uint4*)(gdst + j * 8) = *(const uint4*)(src + j * 8);
  }
}

// Output projection: A=Yb [4096][2048], B=wpb [2048][2048], out fp32.
// fp32 epilogue staged through LDS in two 64-row passes (32 KB each).
__global__ __launch_bounds__(256)
void gemm_proj_bf16(const unsigned short* __restrict__ Yb, const unsigned short* __restrict__ wpb,
                    float* __restrict__ out) {
  __shared__ short smem[17408];
  short* As = smem;
  short* Bs = smem + 8192;
  f32x4 acc[4][4];
#pragma unroll
  for (int i = 0; i < 4; ++i)
#pragma unroll
    for (int j = 0; j < 4; ++j) acc[i][j] = (f32x4){0.f, 0.f, 0.f, 0.f};

  const int m0 = blockIdx.y * 128, n0 = blockIdx.x * 128;
  gemm_core_glds(Yb, wpb, CH, m0, n0, As, Bs, acc);

  const int tid = threadIdx.x, lane = tid & 63, wid = tid >> 6;
  const int wr = wid >> 1, wc = wid & 1, lr = lane & 15, lg = lane >> 4;
  float* fb = (float*)smem;          // [64][132] fp32 = 33792 B
  for (int p = 0; p < 2; ++p) {
    if (wr == p) {
#pragma unroll
      for (int fm = 0; fm < 4; ++fm)
#pragma unroll
        for (int fn = 0; fn < 4; ++fn)
#pragma unroll
          for (int r = 0; r < 4; ++r)
            fb[(fm * 16 + lg * 4 + r) * 132 + wc * 64 + fn * 16 + lr] = acc[fm][fn][r];
    }
    __syncthreads();
    int row = tid >> 2, seg = tid & 3;         // 128B per thread, coalesced
    float* dst = out + (size_t)(m0 + p * 64 + row) * CH + n0 + seg * 32;
    const float* src = fb + row * 132 + seg * 32;
#pragma unroll
    for (int j = 0; j < 8; ++j)
      *(uint4*)(dst + j * 4) = *(const uint4*)(src + j * 4);
    __syncthreads();
  }
}

// ---------------------------------------------------------------------------
// MFMA flash attention (validated structure). Only change: Y epilogue now
// staged through LDS -> coalesced uint4 stores (was scattered 2B).
// ---------------------------------------------------------------------------
__global__ __launch_bounds__(256)
void attn_mfma(const unsigned short* __restrict__ Qb, const unsigned short* __restrict__ Kb,
               const unsigned short* __restrict__ Vtb, const int* __restrict__ mask,
               unsigned short* __restrict__ Yb) {
  __shared__ short asmem[12032];
  short* Kls = asmem;                // 32*136 = 4352
  short* Vls = asmem + 4352;         // 128*40 = 5120
  short* Pls = asmem + 9472;         // 4*16*40 = 2560
  const int tid = threadIdx.x, lane = tid & 63, wid = tid >> 6;
  const int lr = lane & 15, lg = lane >> 4;
  const int bh = blockIdx.y, b = bh >> 4, h = bh & 15;
  const int q0 = blockIdx.x * 64 + wid * 16;

  short8 qf[4];
  const unsigned short* qptr = Qb + ((size_t)bh * SEQ + q0 + lr) * HDIM + lg * 8;
#pragma unroll
  for (int dc = 0; dc < 4; ++dc) qf[dc] = *(const short8*)(qptr + dc * 32);

  f32x4 O[8];
#pragma unroll
  for (int i = 0; i < 8; ++i) O[i] = (f32x4){0.f, 0.f, 0.f, 0.f};
  float mrow[4] = {-3.0e38f, -3.0e38f, -3.0e38f, -3.0e38f};
  float lrow[4] = {0.f, 0.f, 0.f, 0.f};

  const unsigned short* kbase = Kb + (size_t)bh * SEQ * HDIM;
  const unsigned short* vbase = Vtb + (size_t)bh * HDIM * SEQ;
  short* Pw = Pls + wid * (16 * 40);
  const int* maskrow = mask + b * SEQ;

  for (int kt = 0; kt < SEQ; kt += 32) {
    __syncthreads();
    {   // stage K tile [32][128] and Vt tile [128][32]
      int r = tid >> 3, s = tid & 7;
      const unsigned short* g = kbase + (size_t)(kt + r) * HDIM + s * 16;
      uint4 u0 = *(const uint4*)g, u1 = *(const uint4*)(g + 8);
      *(uint4*)(Kls + r * 136 + s * 16) = u0;
      *(uint4*)(Kls + r * 136 + s * 16 + 8) = u1;
      int d = tid >> 1, s2 = tid & 1;
      const unsigned short* gv = vbase + (size_t)d * SEQ + kt + s2 * 16;
      uint4 v0 = *(const uint4*)gv, v1 = *(const uint4*)(gv + 8);
      *(uint4*)(Vls + d * 40 + s2 * 16) = v0;
      *(uint4*)(Vls + d * 40 + s2 * 16 + 8) = v1;
    }
    __syncthreads();

    f32x4 s0 = (f32x4){0.f, 0.f, 0.f, 0.f}, s1 = (f32x4){0.f, 0.f, 0.f, 0.f};
#pragma unroll
    for (int dc = 0; dc < 4; ++dc) {
      short8 k0f = *(const short8*)(Kls + lr * 136 + dc * 32 + lg * 8);
      short8 k1f = *(const short8*)(Kls + (16 + lr) * 136 + dc * 32 + lg * 8);
      s0 = __builtin_amdgcn_mfma_f32_16x16x32_bf16(qf[dc], k0f, s0, 0, 0, 0);
      s1 = __builtin_amdgcn_mfma_f32_16x16x32_bf16(qf[dc], k1f, s1, 0, 0, 0);
    }

    float b0 = maskrow[kt + lr] ? 0.f : -1.0e30f;
    float b1 = maskrow[kt + 16 + lr] ? 0.f : -1.0e30f;
    float corr[4];
#pragma unroll
    for (int r = 0; r < 4; ++r) {
      float a0 = s0[r] + b0, a1 = s1[r] + b1;
      float tm = fmaxf(a0, a1);
      tm = fmaxf(tm, __shfl_xor(tm, 1));
      tm = fmaxf(tm, __shfl_xor(tm, 2));
      tm = fmaxf(tm, __shfl_xor(tm, 4));
      tm = fmaxf(tm, __shfl_xor(tm, 8));
      float mn = fmaxf(mrow[r], tm);
      corr[r] = __expf(mrow[r] - mn);
      float p0 = __expf(a0 - mn), p1 = __expf(a1 - mn);
      mrow[r] = mn;
      float rs = p0 + p1;
      rs += __shfl_xor(rs, 1);
      rs += __shfl_xor(rs, 2);
      rs += __shfl_xor(rs, 4);
      rs += __shfl_xor(rs, 8);
      lrow[r] = lrow[r] * corr[r] + rs;
      Pw[(lg * 4 + r) * 40 + lr] = (short)f2bf(p0);
      Pw[(lg * 4 + r) * 40 + 16 + lr] = (short)f2bf(p1);
    }
#pragma unroll
    for (int db = 0; db < 8; ++db)
#pragma unroll
      for (int r = 0; r < 4; ++r) O[db][r] *= corr[r];

    short8 pa = *(const short8*)(Pw + lr * 40 + lg * 8);
#pragma unroll
    for (int db = 0; db < 8; ++db) {
      short8 vb = *(const short8*)(Vls + (db * 16 + lr) * 40 + lg * 8);
      O[db] = __builtin_amdgcn_mfma_f32_16x16x32_bf16(pa, vb, O[db], 0, 0, 0);
    }
  }

  float inv[4];
#pragma unroll
  for (int r = 0; r < 4; ++r) inv[r] = 1.0f / lrow[r];

  // Y epilogue via LDS: [64 q][136 d] then 64B/thread coalesced stores
  short* Ols = asmem;
  __syncthreads();                   // all waves done reading K/V/P LDS
#pragma unroll
  for (int db = 0; db < 8; ++db)
#pragma unroll
    for (int r = 0; r < 4; ++r)
      Ols[(wid * 16 + lg * 4 + r) * 136 + db * 16 + lr] = (short)f2bf(O[db][r] * inv[r]);
  __syncthreads();
  {
    int row = tid >> 2, seg = tid & 3;
    unsigned short* dst =
        Yb + ((size_t)(b * SEQ + blockIdx.x * 64 + row)) * CH + h * HDIM + seg * 32;
    const short* src = Ols + row * 136 + seg * 32;
#pragma unroll
    for (int j = 0; j < 4; ++j)
      *(uint4*)(dst + j * 8) = *(const uint4*)(src + j * 8);
  }
}

// ---------------------------------------------------------------------------
extern "C" void kernel_launch(void* const* d_in, const int* in_sizes, int n_in,
                              void* d_out, int out_size, void* d_ws, size_t ws_size,
                              hipStream_t stream) {
  const float* x      = (const float*)d_in[0];   // [B,T,C]
  const float* w_attn = (const float*)d_in[1];   // [3C,C]
  const float* w_proj = (const float*)d_in[2];   // [C,C]
  const int*   mask   = (const int*)d_in[3];     // [B,T]
  float* out = (float*)d_out;                    // [B,T,C] fp32

  char* ws = (char*)d_ws;
  unsigned short* xb  = (unsigned short*)(ws);
  unsigned short* wab = (unsigned short*)(ws + 16777216);
  unsigned short* wpb = (unsigned short*)(ws + 41943040);
  unsigned short* Qb  = (unsigned short*)(ws + 50331648);
  unsigned short* Kb  = (unsigned short*)(ws + 67108864);
  unsigned short* Vtb = (unsigned short*)(ws + 83886080);
  unsigned short* Yb  = (unsigned short*)(ws + 100663296);   // 117.44 MB total

  cast_bf16<<<2048, 256, 0, stream>>>(x, xb, (NB * SEQ * CH) / 4);
  cast_bf16<<<2048, 256, 0, stream>>>(w_attn, wab, (3 * CH * CH) / 4);
  cast_bf16<<<2048, 256, 0, stream>>>(w_proj, wpb, (CH * CH) / 4);

  gemm_qkv_bf16<<<dim3(3 * CH / 128, NB * SEQ / 128), 256, 0, stream>>>(xb, wab, Qb, Kb, Vtb);
  attn_mfma<<<dim3(SEQ / 64, NB * NH), 256, 0, stream>>>(Qb, Kb, Vtb, mask, Yb);
  gemm_proj_bf16<<<dim3(CH / 128, NB * SEQ / 128), 256, 0, stream>>>(Yb, wpb, out);
}

// Round 12
// 466.653 us; speedup vs baseline: 6.7097x; 1.0084x over previous
//
#include <hip/hip_runtime.h>
#include <hip/hip_bf16.h>

#define NB   4
#define NH   16
#define SEQ  1024
#define CH   2048
#define HDIM 128

typedef float f32x4 __attribute__((ext_vector_type(4)));
typedef short short8 __attribute__((ext_vector_type(8)));

// fp32 -> bf16 round-to-nearest-even
static __device__ __forceinline__ unsigned short f2bf(float f) {
  unsigned u = __builtin_bit_cast(unsigned, f);
  u += 0x7FFFu + ((u >> 16) & 1u);
  return (unsigned short)(u >> 16);
}

// async global->LDS, 16B per lane: LDS dest = wave-uniform base + lane*16,
// global src = per-lane address.
#define GLOAD16(g, l)                                                        \
  __builtin_amdgcn_global_load_lds(                                          \
      (const __attribute__((address_space(1))) void*)(g),                    \
      (__attribute__((address_space(3))) void*)(l), 16, 0, 0)

__global__ __launch_bounds__(256)
void cast_bf16(const float* __restrict__ in, unsigned short* __restrict__ out, int n4) {
  int i = blockIdx.x * 256 + threadIdx.x;
  int stride = gridDim.x * 256;
  for (; i < n4; i += stride) {
    float4 v = ((const float4*)in)[i];
    ushort4 o;
    o.x = f2bf(v.x); o.y = f2bf(v.y); o.z = f2bf(v.z); o.w = f2bf(v.w);
    ((ushort4*)out)[i] = o;
  }
}

// ---------------------------------------------------------------------------
// QKV GEMM, 256x256 tile, BK=64, 8 waves (2 Mrow x 4 Ncol), 512 threads.
// Double-buffered LDS staging (2 x (A 256x64 + B 256x64) bf16 = 128 KB):
// iteration kt issues global_load_lds for tile kt+1 into buf^1, then runs
// 64 MFMA/wave on buf, then ONE barrier (its vmcnt(0) drain completes after
// the loads already landed under compute). Linear LDS layout (no swizzle).
// Epilogues via LDS -> full-line coalesced stores (validated in round 8).
// ---------------------------------------------------------------------------
__global__ __launch_bounds__(512, 2)
void gemm_qkv_256(const unsigned short* __restrict__ xb, const unsigned short* __restrict__ wab,
                  unsigned short* __restrict__ Qb, unsigned short* __restrict__ Kb,
                  unsigned short* __restrict__ Vtb) {
  __shared__ short smem[65536];          // 128 KB
  const int tid = threadIdx.x, lane = tid & 63, wid = tid >> 6;  // 8 waves
  const int wr = wid >> 2, wc = wid & 3, lr = lane & 15, lg = lane >> 4;
  const int sr = lane >> 3, sk = (lane & 7) * 8;

  // bijective XCD swizzle: 384 blocks, 48 per XCD -> contiguous by-rows per XCD
  const int lid = blockIdx.y * 24 + blockIdx.x;
  const int swz = (lid & 7) * 48 + (lid >> 3);
  const int bx = swz % 24, by = swz / 24;
  const int m0 = by * 256, n0 = bx * 256;

  f32x4 acc[8][4];
#pragma unroll
  for (int i = 0; i < 8; ++i)
#pragma unroll
    for (int j = 0; j < 4; ++j) acc[i][j] = (f32x4){0.f, 0.f, 0.f, 0.f};

  // stage tile (k0) into buffer b: 32 chunks x 8 rows, per matrix
#define STAGE_TILE(b, k0)                                                      \
  do {                                                                         \
    short* As_ = smem + (b) * 32768;                                           \
    short* Bs_ = As_ + 16384;                                                  \
    _Pragma("unroll")                                                          \
    for (int p = 0; p < 4; ++p) {                                              \
      int c = wid * 4 + p;                                                     \
      GLOAD16(xb + (size_t)(m0 + c * 8 + sr) * CH + (k0) + sk, As_ + c * 512); \
      GLOAD16(wab + (size_t)(n0 + c * 8 + sr) * CH + (k0) + sk, Bs_ + c * 512);\
    }                                                                          \
  } while (0)

  STAGE_TILE(0, 0);
  __syncthreads();                       // tile 0 visible
  int cur = 0;
  for (int kt = 0; kt < 32; ++kt) {
    if (kt + 1 < 32) STAGE_TILE(cur ^ 1, (kt + 1) * 64);   // overlaps compute
    const short* As = smem + cur * 32768;
    const short* Bs = As + 16384;
#pragma unroll
    for (int kc = 0; kc < 2; ++kc) {
      short8 bfr[4];
#pragma unroll
      for (int fn = 0; fn < 4; ++fn)
        bfr[fn] = *(const short8*)(Bs + (wc * 64 + fn * 16 + lr) * 64 + kc * 32 + lg * 8);
#pragma unroll
      for (int fm = 0; fm < 8; ++fm) {
        short8 af = *(const short8*)(As + (wr * 128 + fm * 16 + lr) * 64 + kc * 32 + lg * 8);
#pragma unroll
        for (int fn = 0; fn < 4; ++fn)
          acc[fm][fn] = __builtin_amdgcn_mfma_f32_16x16x32_bf16(af, bfr[fn], acc[fm][fn], 0, 0, 0);
      }
    }
    __syncthreads();                     // drains next-tile loads; frees cur
    cur ^= 1;
  }
#undef STAGE_TILE

  const int which = n0 >> 11;            // 0=Q 1=K 2=V (2048%256==0: no straddle)
  const int h0 = (n0 & 2047) >> 7;       // first of the two heads in this tile
  const int bb = m0 >> 10, t0 = m0 & 1023;

  if (which < 2) {
    unsigned short* dst0 = (which == 0) ? Qb : Kb;
    const float sc = (which == 0) ? 0.08838834764831843f : 1.0f;
    // two t-half passes through LDS [128 t][264 d]
    for (int p = 0; p < 2; ++p) {
      if (wr == p) {
#pragma unroll
        for (int fm = 0; fm < 8; ++fm)
#pragma unroll
          for (int fn = 0; fn < 4; ++fn)
#pragma unroll
            for (int r = 0; r < 4; ++r)
              smem[(fm * 16 + lg * 4 + r) * 264 + wc * 64 + fn * 16 + lr] =
                  (short)f2bf(acc[fm][fn][r] * sc);
      }
      __syncthreads();
      int row = tid >> 2, seg = tid & 3;   // 128B/thread coalesced
      int h = h0 + (seg >> 1), d0 = (seg & 1) * 64;
      unsigned short* dst =
          dst0 + (((size_t)(bb * NH + h)) * SEQ + t0 + p * 128 + row) * HDIM + d0;
      const short* src = smem + row * 264 + seg * 64;
#pragma unroll
      for (int j = 0; j < 8; ++j)
        *(uint4*)(dst + j * 8) = *(const uint4*)(src + j * 8);
      __syncthreads();
    }
  } else {
    // V transposed: two t-half passes through LDS [256 d][136 t]
    for (int p = 0; p < 2; ++p) {
      if (wr == p) {
#pragma unroll
        for (int fm = 0; fm < 8; ++fm)
#pragma unroll
          for (int fn = 0; fn < 4; ++fn)
#pragma unroll
            for (int r = 0; r < 4; ++r)
              smem[(wc * 64 + fn * 16 + lr) * 136 + fm * 16 + lg * 4 + r] =
                  (short)f2bf(acc[fm][fn][r]);
      }
      __syncthreads();
      int d = tid >> 1, sg = tid & 1;      // 128B/thread coalesced
      int h = h0 + (d >> 7), dl = d & 127;
      unsigned short* dst =
          Vtb + (((size_t)(bb * NH + h)) * HDIM + dl) * SEQ + t0 + p * 128 + sg * 64;
      const short* src = smem + d * 136 + sg * 64;
#pragma unroll
      for (int j = 0; j < 8; ++j)
        *(uint4*)(dst + j * 8) = *(const uint4*)(src + j * 8);
      __syncthreads();
    }
  }
}

// ---------------------------------------------------------------------------
// 128x128 GEMM core (validated round 8) — still used by the output projection.
// ---------------------------------------------------------------------------
__device__ __forceinline__ void gemm_core_glds(
    const unsigned short* __restrict__ A, const unsigned short* __restrict__ B,
    int K, int m0, int n0, short* As, short* Bs, f32x4 acc[4][4]) {
  const int tid = threadIdx.x, lane = tid & 63, wid = tid >> 6;
  const int wr = wid >> 1, wc = wid & 1, lr = lane & 15, lg = lane >> 4;
  const int sr = lane >> 3;
  const int sk = (lane & 7) * 8;

  for (int k0 = 0; k0 < K; k0 += 64) {
    __syncthreads();
#pragma unroll
    for (int p = 0; p < 4; ++p) {
      int c = wid * 4 + p;
      GLOAD16(A + (size_t)(m0 + c * 8 + sr) * K + k0 + sk, As + c * 512);
      GLOAD16(B + (size_t)(n0 + c * 8 + sr) * K + k0 + sk, Bs + c * 512);
    }
    __syncthreads();
#pragma unroll
    for (int kc = 0; kc < 2; ++kc) {
      short8 af[4], bf[4];
#pragma unroll
      for (int f = 0; f < 4; ++f) {
        af[f] = *(const short8*)(As + (wr * 64 + f * 16 + lr) * 64 + kc * 32 + lg * 8);
        bf[f] = *(const short8*)(Bs + (wc * 64 + f * 16 + lr) * 64 + kc * 32 + lg * 8);
      }
#pragma unroll
      for (int fm = 0; fm < 4; ++fm)
#pragma unroll
        for (int fn = 0; fn < 4; ++fn)
          acc[fm][fn] = __builtin_amdgcn_mfma_f32_16x16x32_bf16(af[fm], bf[fn], acc[fm][fn], 0, 0, 0);
    }
  }
  __syncthreads();
}

// Output projection: A=Yb [4096][2048], B=wpb [2048][2048], out fp32.
__global__ __launch_bounds__(256)
void gemm_proj_bf16(const unsigned short* __restrict__ Yb, const unsigned short* __restrict__ wpb,
                    float* __restrict__ out) {
  __shared__ short smem[17408];
  short* As = smem;
  short* Bs = smem + 8192;
  f32x4 acc[4][4];
#pragma unroll
  for (int i = 0; i < 4; ++i)
#pragma unroll
    for (int j = 0; j < 4; ++j) acc[i][j] = (f32x4){0.f, 0.f, 0.f, 0.f};

  const int m0 = blockIdx.y * 128, n0 = blockIdx.x * 128;
  gemm_core_glds(Yb, wpb, CH, m0, n0, As, Bs, acc);

  const int tid = threadIdx.x, lane = tid & 63, wid = tid >> 6;
  const int wr = wid >> 1, wc = wid & 1, lr = lane & 15, lg = lane >> 4;
  float* fb = (float*)smem;          // [64][132] fp32
  for (int p = 0; p < 2; ++p) {
    if (wr == p) {
#pragma unroll
      for (int fm = 0; fm < 4; ++fm)
#pragma unroll
        for (int fn = 0; fn < 4; ++fn)
#pragma unroll
          for (int r = 0; r < 4; ++r)
            fb[(fm * 16 + lg * 4 + r) * 132 + wc * 64 + fn * 16 + lr] = acc[fm][fn][r];
    }
    __syncthreads();
    int row = tid >> 2, seg = tid & 3;
    float* dst = out + (size_t)(m0 + p * 64 + row) * CH + n0 + seg * 32;
    const float* src = fb + row * 132 + seg * 32;
#pragma unroll
    for (int j = 0; j < 8; ++j)
      *(uint4*)(dst + j * 4) = *(const uint4*)(src + j * 4);
    __syncthreads();
  }
}

// ---------------------------------------------------------------------------
// MFMA flash attention (validated round 8, unchanged).
// ---------------------------------------------------------------------------
__global__ __launch_bounds__(256)
void attn_mfma(const unsigned short* __restrict__ Qb, const unsigned short* __restrict__ Kb,
               const unsigned short* __restrict__ Vtb, const int* __restrict__ mask,
               unsigned short* __restrict__ Yb) {
  __shared__ short asmem[12032];
  short* Kls = asmem;                // 32*136
  short* Vls = asmem + 4352;         // 128*40
  short* Pls = asmem + 9472;         // 4*16*40
  const int tid = threadIdx.x, lane = tid & 63, wid = tid >> 6;
  const int lr = lane & 15, lg = lane >> 4;
  const int bh = blockIdx.y, b = bh >> 4, h = bh & 15;
  const int q0 = blockIdx.x * 64 + wid * 16;

  short8 qf[4];
  const unsigned short* qptr = Qb + ((size_t)bh * SEQ + q0 + lr) * HDIM + lg * 8;
#pragma unroll
  for (int dc = 0; dc < 4; ++dc) qf[dc] = *(const short8*)(qptr + dc * 32);

  f32x4 O[8];
#pragma unroll
  for (int i = 0; i < 8; ++i) O[i] = (f32x4){0.f, 0.f, 0.f, 0.f};
  float mrow[4] = {-3.0e38f, -3.0e38f, -3.0e38f, -3.0e38f};
  float lrow[4] = {0.f, 0.f, 0.f, 0.f};

  const unsigned short* kbase = Kb + (size_t)bh * SEQ * HDIM;
  const unsigned short* vbase = Vtb + (size_t)bh * HDIM * SEQ;
  short* Pw = Pls + wid * (16 * 40);
  const int* maskrow = mask + b * SEQ;

  for (int kt = 0; kt < SEQ; kt += 32) {
    __syncthreads();
    {
      int r = tid >> 3, s = tid & 7;
      const unsigned short* g = kbase + (size_t)(kt + r) * HDIM + s * 16;
      uint4 u0 = *(const uint4*)g, u1 = *(const uint4*)(g + 8);
      *(uint4*)(Kls + r * 136 + s * 16) = u0;
      *(uint4*)(Kls + r * 136 + s * 16 + 8) = u1;
      int d = tid >> 1, s2 = tid & 1;
      const unsigned short* gv = vbase + (size_t)d * SEQ + kt + s2 * 16;
      uint4 v0 = *(const uint4*)gv, v1 = *(const uint4*)(gv + 8);
      *(uint4*)(Vls + d * 40 + s2 * 16) = v0;
      *(uint4*)(Vls + d * 40 + s2 * 16 + 8) = v1;
    }
    __syncthreads();

    f32x4 s0 = (f32x4){0.f, 0.f, 0.f, 0.f}, s1 = (f32x4){0.f, 0.f, 0.f, 0.f};
#pragma unroll
    for (int dc = 0; dc < 4; ++dc) {
      short8 k0f = *(const short8*)(Kls + lr * 136 + dc * 32 + lg * 8);
      short8 k1f = *(const short8*)(Kls + (16 + lr) * 136 + dc * 32 + lg * 8);
      s0 = __builtin_amdgcn_mfma_f32_16x16x32_bf16(qf[dc], k0f, s0, 0, 0, 0);
      s1 = __builtin_amdgcn_mfma_f32_16x16x32_bf16(qf[dc], k1f, s1, 0, 0, 0);
    }

    float b0 = maskrow[kt + lr] ? 0.f : -1.0e30f;
    float b1 = maskrow[kt + 16 + lr] ? 0.f : -1.0e30f;
    float corr[4];
#pragma unroll
    for (int r = 0; r < 4; ++r) {
      float a0 = s0[r] + b0, a1 = s1[r] + b1;
      float tm = fmaxf(a0, a1);
      tm = fmaxf(tm, __shfl_xor(tm, 1));
      tm = fmaxf(tm, __shfl_xor(tm, 2));
      tm = fmaxf(tm, __shfl_xor(tm, 4));
      tm = fmaxf(tm, __shfl_xor(tm, 8));
      float mn = fmaxf(mrow[r], tm);
      corr[r] = __expf(mrow[r] - mn);
      float p0 = __expf(a0 - mn), p1 = __expf(a1 - mn);
      mrow[r] = mn;
      float rs = p0 + p1;
      rs += __shfl_xor(rs, 1);
      rs += __shfl_xor(rs, 2);
      rs += __shfl_xor(rs, 4);
      rs += __shfl_xor(rs, 8);
      lrow[r] = lrow[r] * corr[r] + rs;
      Pw[(lg * 4 + r) * 40 + lr] = (short)f2bf(p0);
      Pw[(lg * 4 + r) * 40 + 16 + lr] = (short)f2bf(p1);
    }
#pragma unroll
    for (int db = 0; db < 8; ++db)
#pragma unroll
      for (int r = 0; r < 4; ++r) O[db][r] *= corr[r];

    short8 pa = *(const short8*)(Pw + lr * 40 + lg * 8);
#pragma unroll
    for (int db = 0; db < 8; ++db) {
      short8 vb = *(const short8*)(Vls + (db * 16 + lr) * 40 + lg * 8);
      O[db] = __builtin_amdgcn_mfma_f32_16x16x32_bf16(pa, vb, O[db], 0, 0, 0);
    }
  }

  float inv[4];
#pragma unroll
  for (int r = 0; r < 4; ++r) inv[r] = 1.0f / lrow[r];

  short* Ols = asmem;
  __syncthreads();
#pragma unroll
  for (int db = 0; db < 8; ++db)
#pragma unroll
    for (int r = 0; r < 4; ++r)
      Ols[(wid * 16 + lg * 4 + r) * 136 + db * 16 + lr] = (short)f2bf(O[db][r] * inv[r]);
  __syncthreads();
  {
    int row = tid >> 2, seg = tid & 3;
    unsigned short* dst =
        Yb + ((size_t)(b * SEQ + blockIdx.x * 64 + row)) * CH + h * HDIM + seg * 32;
    const short* src = Ols + row * 136 + seg * 32;
#pragma unroll
    for (int j = 0; j < 4; ++j)
      *(uint4*)(dst + j * 8) = *(const uint4*)(src + j * 8);
  }
}

// ---------------------------------------------------------------------------
extern "C" void kernel_launch(void* const* d_in, const int* in_sizes, int n_in,
                              void* d_out, int out_size, void* d_ws, size_t ws_size,
                              hipStream_t stream) {
  const float* x      = (const float*)d_in[0];   // [B,T,C]
  const float* w_attn = (const float*)d_in[1];   // [3C,C]
  const float* w_proj = (const float*)d_in[2];   // [C,C]
  const int*   mask   = (const int*)d_in[3];     // [B,T]
  float* out = (float*)d_out;                    // [B,T,C] fp32

  char* ws = (char*)d_ws;
  unsigned short* xb  = (unsigned short*)(ws);
  unsigned short* wab = (unsigned short*)(ws + 16777216);
  unsigned short* wpb = (unsigned short*)(ws + 41943040);
  unsigned short* Qb  = (unsigned short*)(ws + 50331648);
  unsigned short* Kb  = (unsigned short*)(ws + 67108864);
  unsigned short* Vtb = (unsigned short*)(ws + 83886080);
  unsigned short* Yb  = (unsigned short*)(ws + 100663296);   // 117.44 MB total

  cast_bf16<<<2048, 256, 0, stream>>>(x, xb, (NB * SEQ * CH) / 4);
  cast_bf16<<<2048, 256, 0, stream>>>(w_attn, wab, (3 * CH * CH) / 4);
  cast_bf16<<<2048, 256, 0, stream>>>(w_proj, wpb, (CH * CH) / 4);

  gemm_qkv_256<<<dim3(24, 16), 512, 0, stream>>>(xb, wab, Qb, Kb, Vtb);
  attn_mfma<<<dim3(SEQ / 64, NB * NH), 256, 0, stream>>>(Qb, Kb, Vtb, mask, Yb);
  gemm_proj_bf16<<<dim3(CH / 128, NB * SEQ / 128), 256, 0, stream>>>(Yb, wpb, out);
}